// Round 6
// baseline (3329.723 us; speedup 1.0000x reference)
//
#include <hip/hip_runtime.h>
#include <cmath>

#define LRELU(x) ((x) > 0.0f ? (x) : 0.01f * (x))

typedef __attribute__((ext_vector_type(8))) short short8;
typedef __attribute__((ext_vector_type(4))) float f32x4;
typedef __attribute__((ext_vector_type(2))) unsigned uint2v;

constexpr int RS = 1032;   // LDS master row stride (shorts); row*RS*2 is 8B-aligned
constexpr int ROWS = 32;   // rows per block: 66KB LDS -> 2 blocks/CU (4 waves/SIMD)

__device__ __forceinline__ unsigned short f2bf(float f) {
    unsigned u = __float_as_uint(f);
    unsigned r = (u + 0x7fff + ((u >> 16) & 1)) >> 16;   // RNE
    return (unsigned short)r;
}
__device__ __forceinline__ float bf2f(unsigned short h) {
    return __uint_as_float((unsigned)h << 16);
}
__device__ __forceinline__ unsigned pk2(unsigned short a, unsigned short b) {
    return (unsigned)a | ((unsigned)b << 16);
}

// ---------------------------------------------------------------------------
// sgrid[t][c] = sin(r_t * 2^((c/2)/2)), r_t=(t-128)*pi/256  (256 x 32)
// ---------------------------------------------------------------------------
__global__ void sgrid_kernel(float* __restrict__ sg) {
    int idx = blockIdx.x * blockDim.x + threadIdx.x;
    if (idx >= 256 * 32) return;
    int t = idx >> 5, c = idx & 31;
    double r = (double)(t - 128) * 3.14159265358979323846 / 256.0;
    double scale = exp2(0.5 * (double)(c >> 1));
    sg[idx] = (float)sin(r * scale);
}

// ---------------------------------------------------------------------------
// Grouped 3x3 conv + lrelu; weights staged coalesced into LDS.
// ---------------------------------------------------------------------------
__global__ __launch_bounds__(256) void conv_lds(
    const float* __restrict__ x, const float* __restrict__ w,
    const float* __restrict__ bias, float* __restrict__ y,
    int Cin_g, int Cout_g, int Hin, int pad) {
    __shared__ float wsh[6912];
    __shared__ float red[256];
    int oc = blockIdx.x;
    int Hout = pad ? Hin : Hin - 2;
    int t = threadIdx.x;
    int nw = Cin_g * 9;
    const float* wb = w + (size_t)oc * nw;
    for (int idx = t; idx < nw; idx += 256) wsh[idx] = wb[idx];
    __syncthreads();
    int p = t & 63, ch = t >> 6;
    int oy = p / Hout, ox = p % Hout;
    int g = oc / Cout_g;
    const float* xb = x + (size_t)g * Cin_g * Hin * Hin;
    bool valid = p < Hout * Hout;
    int S = (Cin_g + 3) >> 2;
    int ic0 = ch * S, ic1 = min(Cin_g, ic0 + S);
    float acc = 0.f;
    if (valid) {
        for (int ic = ic0; ic < ic1; ++ic) {
            const float* xc = xb + (size_t)ic * Hin * Hin;
            const float* wc = wsh + ic * 9;
            #pragma unroll
            for (int ky = 0; ky < 3; ++ky) {
                int iy = oy + ky - pad;
                if (iy < 0 || iy >= Hin) continue;
                #pragma unroll
                for (int kx = 0; kx < 3; ++kx) {
                    int ix = ox + kx - pad;
                    if (ix < 0 || ix >= Hin) continue;
                    acc = fmaf(xc[iy * Hin + ix], wc[ky * 3 + kx], acc);
                }
            }
        }
    }
    red[t] = acc;
    __syncthreads();
    if (t < 64 && valid) {
        float s = red[t] + red[t + 64] + red[t + 128] + red[t + 192] + bias[oc];
        y[(size_t)oc * Hout * Hout + p] = LRELU(s);
    }
}

// ---------------------------------------------------------------------------
// c1[o] = b1[o] + feat . w1[o][32:]
// ---------------------------------------------------------------------------
__global__ void feat_c1_kernel(const float* __restrict__ feat, const float* __restrict__ w1,
                               const float* __restrict__ b1, float* __restrict__ c1) {
    int o = (blockIdx.x * blockDim.x + threadIdx.x) >> 6;
    int lane = threadIdx.x & 63;
    if (o >= 1024) return;
    const float* wr = w1 + (size_t)o * 2080 + 32;
    float sum = 0.f;
    for (int k = lane; k < 2048; k += 64) sum += feat[k] * wr[k];
    #pragma unroll
    for (int off = 32; off; off >>= 1) sum += __shfl_xor(sum, off);
    if (lane == 0) c1[o] = sum + b1[o];
}

// ---------------------------------------------------------------------------
// wn_cvt: bf16 copy of v and s = g/||v|| in one pass (block per row)
// ---------------------------------------------------------------------------
__global__ __launch_bounds__(256) void wn_cvt(const float* __restrict__ v, const float* __restrict__ g,
                                              unsigned short* __restrict__ vbf, float* __restrict__ s,
                                              int K) {
    __shared__ float red[256];
    int r = blockIdx.x, t = threadIdx.x;
    const float* vr = v + (size_t)r * K;
    float sum = 0.f;
    for (int k = t; k < K; k += 256) {
        float x = vr[k];
        sum = fmaf(x, x, sum);
        vbf[(size_t)r * K + k] = f2bf(x);
    }
    red[t] = sum;
    __syncthreads();
    for (int o = 128; o; o >>= 1) {
        if (t < o) red[t] += red[t + o];
        __syncthreads();
    }
    if (t == 0) s[r] = g[r] / sqrtf(red[0]);
}

__global__ void cvt_w2_kernel(const float* __restrict__ w2, unsigned short* __restrict__ dst) {
    int i = blockIdx.x * 256 + threadIdx.x;
    int r = i >> 10, c = i & 1023;
    dst[i] = f2bf(w2[(size_t)r * 1056 + 32 + c]);
}

// ---------------------------------------------------------------------------
// Px/Py, Qx/Qy separable grid tables
// ---------------------------------------------------------------------------
__global__ void pxy_kernel(const float* __restrict__ sg, const float* __restrict__ w1,
                           const float* __restrict__ c1, float* __restrict__ Px,
                           float* __restrict__ Py) {
    int idx = blockIdx.x * 256 + threadIdx.x;  // 256*1024
    int t = idx >> 10, o = idx & 1023;
    const float* wr = w1 + (size_t)o * 2080;
    const float* sr = sg + t * 32;
    float px = 0.f, py = 0.f;
    #pragma unroll
    for (int k = 0; k < 16; ++k) {
        px = fmaf(sr[2 * k], wr[2 * k], px);
        py = fmaf(sr[2 * k + 1], wr[2 * k + 1], py);
    }
    Px[idx] = px + c1[o];
    Py[idx] = py;
}

__global__ void qxy_kernel(const float* __restrict__ sg, const float* __restrict__ w2,
                           float* __restrict__ Qx, float* __restrict__ Qy) {
    int idx = blockIdx.x * 256 + threadIdx.x;  // 256*512
    int t = idx >> 9, o = idx & 511;
    const float* wr = w2 + (size_t)o * 1056;
    const float* sr = sg + t * 32;
    float qx = 0.f, qy = 0.f;
    #pragma unroll
    for (int k = 0; k < 16; ++k) {
        qx = fmaf(sr[2 * k], wr[2 * k], qx);
        qy = fmaf(sr[2 * k + 1], wr[2 * k + 1], qy);
    }
    Qx[idx] = qx;
    Qy[idx] = qy;
}

// ---------------------------------------------------------------------------
// Fused MLP, 32-row blocks. Swapped-operand MFMA: acc = mfma(w_frag, a_frag)
// -> D[wcol=quad*4+r][actrow=lane&15]: each lane owns 4 consecutive cols at
// a fixed row -> b64 LDS epilogue. Master hi image (bf16) in LDS [32][RS];
// stack-1 lo plane in VGPRs (packed pairs); stack-2 lo in cols 512..1023.
// ---------------------------------------------------------------------------
__device__ __forceinline__ void step1(unsigned short* sm, int w, int l15, int lq,
                                      int srcb, int dstb,
                                      const unsigned short* __restrict__ B,
                                      const float* __restrict__ sc,
                                      const float* __restrict__ bi,
                                      unsigned* lo_half) {
    f32x4 acc[2][4] = {};
    const unsigned short* bbase = B + (size_t)(w * 64 + l15) * 512 + lq * 8;
    const unsigned short* abase = sm + (size_t)l15 * RS + srcb + lq * 8;
    short8 bcur[4];
    #pragma unroll
    for (int nt = 0; nt < 4; ++nt) bcur[nt] = *(const short8*)(bbase + nt * (16 * 512));
    #pragma unroll
    for (int kc = 0; kc < 16; ++kc) {
        short8 bn[4];
        if (kc < 15) {
            #pragma unroll
            for (int nt = 0; nt < 4; ++nt)
                bn[nt] = *(const short8*)(bbase + nt * (16 * 512) + (kc + 1) * 32);
        }
        short8 af[2];
        #pragma unroll
        for (int mt = 0; mt < 2; ++mt)
            af[mt] = *(const short8*)(abase + (size_t)(mt * 16) * RS + kc * 32);
        #pragma unroll
        for (int mt = 0; mt < 2; ++mt)
            #pragma unroll
            for (int nt = 0; nt < 4; ++nt)
                acc[mt][nt] = __builtin_amdgcn_mfma_f32_16x16x32_bf16(bcur[nt], af[mt], acc[mt][nt], 0, 0, 0);
        #pragma unroll
        for (int nt = 0; nt < 4; ++nt) bcur[nt] = bn[nt];
    }
    #pragma unroll
    for (int nt = 0; nt < 4; ++nt) {
        int nb = w * 64 + nt * 16 + lq * 4;
        float4 s4 = *(const float4*)(sc + nb);
        float4 bb = *(const float4*)(bi + nb);
        #pragma unroll
        for (int mt = 0; mt < 2; ++mt) {
            int row = mt * 16 + l15;
            size_t hidx = (size_t)row * RS + dstb + nb;
            uint2v hold = *(uint2v*)(sm + hidx);
            unsigned* lp = lo_half + (mt * 4 + nt) * 2;
            float v0 = LRELU(acc[mt][nt][0] * s4.x + bb.x);
            float v1 = LRELU(acc[mt][nt][1] * s4.y + bb.y);
            float v2 = LRELU(acc[mt][nt][2] * s4.z + bb.z);
            float v3 = LRELU(acc[mt][nt][3] * s4.w + bb.w);
            v0 += bf2f((unsigned short)(hold[0] & 0xffffu)) + bf2f((unsigned short)(lp[0] & 0xffffu));
            v1 += bf2f((unsigned short)(hold[0] >> 16)) + bf2f((unsigned short)(lp[0] >> 16));
            v2 += bf2f((unsigned short)(hold[1] & 0xffffu)) + bf2f((unsigned short)(lp[1] & 0xffffu));
            v3 += bf2f((unsigned short)(hold[1] >> 16)) + bf2f((unsigned short)(lp[1] >> 16));
            unsigned short h0 = f2bf(v0), h1 = f2bf(v1), h2 = f2bf(v2), h3 = f2bf(v3);
            uint2v hnew; hnew[0] = pk2(h0, h1); hnew[1] = pk2(h2, h3);
            *(uint2v*)(sm + hidx) = hnew;
            lp[0] = pk2(f2bf(v0 - bf2f(h0)), f2bf(v1 - bf2f(h1)));
            lp[1] = pk2(f2bf(v2 - bf2f(h2)), f2bf(v3 - bf2f(h3)));
        }
    }
}

__device__ __forceinline__ void step2(unsigned short* sm, int w, int l15, int lq,
                                      int srcb, int dstb,
                                      const unsigned short* __restrict__ B,
                                      const float* __restrict__ sc,
                                      const float* __restrict__ bi) {
    f32x4 acc[2][2] = {};
    const unsigned short* bbase = B + (size_t)(w * 32 + l15) * 256 + lq * 8;
    const unsigned short* abase = sm + (size_t)l15 * RS + srcb + lq * 8;
    short8 bcur[2];
    #pragma unroll
    for (int nt = 0; nt < 2; ++nt) bcur[nt] = *(const short8*)(bbase + nt * (16 * 256));
    #pragma unroll
    for (int kc = 0; kc < 8; ++kc) {
        short8 bn[2];
        if (kc < 7) {
            #pragma unroll
            for (int nt = 0; nt < 2; ++nt)
                bn[nt] = *(const short8*)(bbase + nt * (16 * 256) + (kc + 1) * 32);
        }
        short8 af[2];
        #pragma unroll
        for (int mt = 0; mt < 2; ++mt)
            af[mt] = *(const short8*)(abase + (size_t)(mt * 16) * RS + kc * 32);
        #pragma unroll
        for (int mt = 0; mt < 2; ++mt)
            #pragma unroll
            for (int nt = 0; nt < 2; ++nt)
                acc[mt][nt] = __builtin_amdgcn_mfma_f32_16x16x32_bf16(bcur[nt], af[mt], acc[mt][nt], 0, 0, 0);
        #pragma unroll
        for (int nt = 0; nt < 2; ++nt) bcur[nt] = bn[nt];
    }
    #pragma unroll
    for (int nt = 0; nt < 2; ++nt) {
        int nb = w * 32 + nt * 16 + lq * 4;
        float4 s4 = *(const float4*)(sc + nb);
        float4 bb = *(const float4*)(bi + nb);
        #pragma unroll
        for (int mt = 0; mt < 2; ++mt) {
            int row = mt * 16 + l15;
            size_t hidx = (size_t)row * RS + dstb + nb;
            uint2v hold = *(uint2v*)(sm + hidx);
            uint2v lold = *(uint2v*)(sm + hidx + 512);
            float v0 = LRELU(acc[mt][nt][0] * s4.x + bb.x);
            float v1 = LRELU(acc[mt][nt][1] * s4.y + bb.y);
            float v2 = LRELU(acc[mt][nt][2] * s4.z + bb.z);
            float v3 = LRELU(acc[mt][nt][3] * s4.w + bb.w);
            v0 += bf2f((unsigned short)(hold[0] & 0xffffu)) + bf2f((unsigned short)(lold[0] & 0xffffu));
            v1 += bf2f((unsigned short)(hold[0] >> 16)) + bf2f((unsigned short)(lold[0] >> 16));
            v2 += bf2f((unsigned short)(hold[1] & 0xffffu)) + bf2f((unsigned short)(lold[1] & 0xffffu));
            v3 += bf2f((unsigned short)(hold[1] >> 16)) + bf2f((unsigned short)(lold[1] >> 16));
            unsigned short h0 = f2bf(v0), h1 = f2bf(v1), h2 = f2bf(v2), h3 = f2bf(v3);
            uint2v hnew; hnew[0] = pk2(h0, h1); hnew[1] = pk2(h2, h3);
            uint2v lnew; lnew[0] = pk2(f2bf(v0 - bf2f(h0)), f2bf(v1 - bf2f(h1)));
            lnew[1] = pk2(f2bf(v2 - bf2f(h2)), f2bf(v3 - bf2f(h3)));
            *(uint2v*)(sm + hidx) = hnew;
            *(uint2v*)(sm + hidx + 512) = lnew;
        }
    }
}

__global__ __launch_bounds__(512, 4) void fused_mlp(
    const float* __restrict__ Px, const float* __restrict__ Py,
    const float* __restrict__ Qx, const float* __restrict__ Qy,
    const unsigned short* __restrict__ m1f, const float* __restrict__ s1f, const float* __restrict__ bf1,
    const unsigned short* __restrict__ m1g, const float* __restrict__ s1g, const float* __restrict__ bg1,
    const unsigned short* __restrict__ w2m, const float* __restrict__ b2,
    const unsigned short* __restrict__ m2f, const float* __restrict__ s2f, const float* __restrict__ bf2_,
    const unsigned short* __restrict__ m2g, const float* __restrict__ s2g, const float* __restrict__ bg2_,
    const float* __restrict__ w3, const float* __restrict__ b3,
    float* __restrict__ out) {
    extern __shared__ unsigned short sm[];     // [ROWS][RS]
    int tid = threadIdx.x;
    int w = tid >> 6, l = tid & 63;
    int l15 = l & 15, lq = l >> 4;
    int n0 = blockIdx.x * ROWS;
    int i = n0 >> 8, jb = n0 & 255;

    unsigned lo_pk[32];   // stack-1 lo plane: [half(2)][mt(2)][nt(4)][pair(2)]

    // ---- P1: mid init; hi -> LDS (b64), lo -> VGPR ----
    #pragma unroll
    for (int h = 0; h < 2; ++h) {
        #pragma unroll
        for (int nt = 0; nt < 4; ++nt) {
            int nb = h * 512 + w * 64 + nt * 16 + lq * 4;
            float4 px4 = *(const float4*)(Px + (size_t)i * 1024 + nb);
            #pragma unroll
            for (int mt = 0; mt < 2; ++mt) {
                int row = mt * 16 + l15;
                float4 py4 = *(const float4*)(Py + (size_t)(jb + row) * 1024 + nb);
                float v0 = LRELU(px4.x + py4.x);
                float v1 = LRELU(px4.y + py4.y);
                float v2 = LRELU(px4.z + py4.z);
                float v3 = LRELU(px4.w + py4.w);
                unsigned short h0 = f2bf(v0), h1 = f2bf(v1), h2 = f2bf(v2), h3 = f2bf(v3);
                uint2v hv; hv[0] = pk2(h0, h1); hv[1] = pk2(h2, h3);
                *(uint2v*)(sm + (size_t)row * RS + nb) = hv;
                unsigned* lp = lo_pk + h * 16 + (mt * 4 + nt) * 2;
                lp[0] = pk2(f2bf(v0 - bf2f(h0)), f2bf(v1 - bf2f(h1)));
                lp[1] = pk2(f2bf(v2 - bf2f(h2)), f2bf(v3 - bf2f(h3)));
            }
        }
    }
    __syncthreads();

    // ---- P2: stack 1 ----
    for (int t = 0; t < 8; ++t) {
        step1(sm, w, l15, lq, 512, 0, m1f + (size_t)t * 512 * 512, s1f + t * 512, bf1 + t * 512, lo_pk);
        __syncthreads();
        step1(sm, w, l15, lq, 0, 512, m1g + (size_t)t * 512 * 512, s1g + t * 512, bg1 + t * 512, lo_pk + 16);
        __syncthreads();
    }

    // ---- P3: h2 = lrelu(Qx+Qy + mid @ w2m^T + b2); overwrite master ----
    {
        f32x4 acc[2][4] = {};
        const unsigned short* bbase = w2m + (size_t)(w * 64 + l15) * 1024 + lq * 8;
        const unsigned short* abase = sm + (size_t)l15 * RS + lq * 8;
        short8 bcur[4];
        #pragma unroll
        for (int nt = 0; nt < 4; ++nt) bcur[nt] = *(const short8*)(bbase + nt * (16 * 1024));
        #pragma unroll
        for (int kc = 0; kc < 32; ++kc) {
            short8 bn[4];
            if (kc < 31) {
                #pragma unroll
                for (int nt = 0; nt < 4; ++nt)
                    bn[nt] = *(const short8*)(bbase + nt * (16 * 1024) + (kc + 1) * 32);
            }
            short8 af[2];
            #pragma unroll
            for (int mt = 0; mt < 2; ++mt)
                af[mt] = *(const short8*)(abase + (size_t)(mt * 16) * RS + kc * 32);
            #pragma unroll
            for (int mt = 0; mt < 2; ++mt)
                #pragma unroll
                for (int nt = 0; nt < 4; ++nt)
                    acc[mt][nt] = __builtin_amdgcn_mfma_f32_16x16x32_bf16(bcur[nt], af[mt], acc[mt][nt], 0, 0, 0);
            #pragma unroll
            for (int nt = 0; nt < 4; ++nt) bcur[nt] = bn[nt];
        }
        __syncthreads();   // all A reads of mid done before overwrite
        #pragma unroll
        for (int nt = 0; nt < 4; ++nt) {
            int nb = w * 64 + nt * 16 + lq * 4;      // 0..511
            float4 qx4 = *(const float4*)(Qx + (size_t)i * 512 + nb);
            float4 b24 = *(const float4*)(b2 + nb);
            #pragma unroll
            for (int mt = 0; mt < 2; ++mt) {
                int row = mt * 16 + l15;
                float4 qy4 = *(const float4*)(Qy + (size_t)(jb + row) * 512 + nb);
                float v0 = LRELU(acc[mt][nt][0] + qx4.x + qy4.x + b24.x);
                float v1 = LRELU(acc[mt][nt][1] + qx4.y + qy4.y + b24.y);
                float v2 = LRELU(acc[mt][nt][2] + qx4.z + qy4.z + b24.z);
                float v3 = LRELU(acc[mt][nt][3] + qx4.w + qy4.w + b24.w);
                unsigned short h0 = f2bf(v0), h1 = f2bf(v1), h2 = f2bf(v2), h3 = f2bf(v3);
                size_t hidx = (size_t)row * RS + nb;
                uint2v hv; hv[0] = pk2(h0, h1); hv[1] = pk2(h2, h3);
                uint2v lv; lv[0] = pk2(f2bf(v0 - bf2f(h0)), f2bf(v1 - bf2f(h1)));
                lv[1] = pk2(f2bf(v2 - bf2f(h2)), f2bf(v3 - bf2f(h3)));
                *(uint2v*)(sm + hidx) = hv;
                *(uint2v*)(sm + hidx + 512) = lv;
            }
        }
    }
    __syncthreads();

    // ---- P4: stack 2 ----
    for (int t = 0; t < 8; ++t) {
        step2(sm, w, l15, lq, 256, 0, m2f + (size_t)t * 256 * 256, s2f + t * 256, bf2_ + t * 256);
        __syncthreads();
        step2(sm, w, l15, lq, 0, 256, m2g + (size_t)t * 256 * 256, s2g + t * 256, bg2_ + t * 256);
        __syncthreads();
    }

    // ---- P5: rgb ----
    #pragma unroll
    for (int rr = 0; rr < 4; ++rr) {
        int row = w * 4 + rr;
        float s0 = 0.f, s1 = 0.f, s2 = 0.f;
        #pragma unroll
        for (int it = 0; it < 8; ++it) {
            int k = it * 64 + l;
            size_t hidx = (size_t)row * RS + k;
            float hv = bf2f(sm[hidx]) + bf2f(sm[hidx + 512]);
            s0 = fmaf(hv, w3[k], s0);
            s1 = fmaf(hv, w3[512 + k], s1);
            s2 = fmaf(hv, w3[1024 + k], s2);
        }
        #pragma unroll
        for (int off = 32; off; off >>= 1) {
            s0 += __shfl_xor(s0, off);
            s1 += __shfl_xor(s1, off);
            s2 += __shfl_xor(s2, off);
        }
        if (l == 0) {
            float v[3] = {s0 + b3[0], s1 + b3[1], s2 + b3[2]};
            #pragma unroll
            for (int c = 0; c < 3; ++c) {
                float sg = 1.0f / (1.0f + expf(-v[c]));
                out[(size_t)c * 65536 + n0 + row] = 1.1f * sg - 0.05f;
            }
        }
    }
}

extern "C" void kernel_launch(void* const* d_in, const int* in_sizes, int n_in,
                              void* d_out, int out_size, void* d_ws, size_t ws_size,
                              hipStream_t stream) {
    const float* feature = (const float*)d_in[0];
    const float* cw1 = (const float*)d_in[1];  const float* cb1 = (const float*)d_in[2];
    const float* cw2 = (const float*)d_in[3];  const float* cb2 = (const float*)d_in[4];
    const float* cw3 = (const float*)d_in[5];  const float* cb3 = (const float*)d_in[6];
    const float* cw4 = (const float*)d_in[7];  const float* cb4 = (const float*)d_in[8];
    const float* cw5 = (const float*)d_in[9];  const float* cb5 = (const float*)d_in[10];
    const float* w1  = (const float*)d_in[11]; const float* b1  = (const float*)d_in[12];
    const float* m1_vf = (const float*)d_in[13]; const float* m1_gf = (const float*)d_in[14];
    const float* m1_bf = (const float*)d_in[15];
    const float* m1_vg = (const float*)d_in[16]; const float* m1_gg = (const float*)d_in[17];
    const float* m1_bg = (const float*)d_in[18];
    const float* w2  = (const float*)d_in[19]; const float* b2  = (const float*)d_in[20];
    const float* m2_vf = (const float*)d_in[21]; const float* m2_gf = (const float*)d_in[22];
    const float* m2_bf = (const float*)d_in[23];
    const float* m2_vg = (const float*)d_in[24]; const float* m2_gg = (const float*)d_in[25];
    const float* m2_bg = (const float*)d_in[26];
    const float* w3  = (const float*)d_in[27]; const float* b3  = (const float*)d_in[28];
    float* out = (float*)d_out;

    float* ws = (float*)d_ws;
    size_t off = 0;
    float* sgrid   = ws + off; off += 256 * 32;
    float* cbA     = ws + off; off += 768 * 64;
    float* cbB     = ws + off; off += 768 * 64;
    float* featbuf = ws + off; off += 2048;
    float* c1      = ws + off; off += 1024;
    float* s1f     = ws + off; off += 8 * 512;
    float* s1g     = ws + off; off += 8 * 512;
    float* s2f     = ws + off; off += 8 * 256;
    float* s2g     = ws + off; off += 8 * 256;
    float* Px      = ws + off; off += 256 * 1024;
    float* Py      = ws + off; off += 256 * 1024;
    float* Qx      = ws + off; off += 256 * 512;
    float* Qy      = ws + off; off += 256 * 512;
    unsigned short* m1f_bf = (unsigned short*)(ws + off); off += (size_t)8 * 512 * 512 / 2;
    unsigned short* m1g_bf = (unsigned short*)(ws + off); off += (size_t)8 * 512 * 512 / 2;
    unsigned short* m2f_bf = (unsigned short*)(ws + off); off += (size_t)8 * 256 * 256 / 2;
    unsigned short* m2g_bf = (unsigned short*)(ws + off); off += (size_t)8 * 256 * 256 / 2;
    unsigned short* w2m_bf = (unsigned short*)(ws + off); off += (size_t)512 * 1024 / 2;

    // ---- constants ----
    sgrid_kernel<<<32, 256, 0, stream>>>(sgrid);
    wn_cvt<<<8 * 512, 256, 0, stream>>>(m1_vf, m1_gf, m1f_bf, s1f, 512);
    wn_cvt<<<8 * 512, 256, 0, stream>>>(m1_vg, m1_gg, m1g_bf, s1g, 512);
    wn_cvt<<<8 * 256, 256, 0, stream>>>(m2_vf, m2_gf, m2f_bf, s2f, 256);
    wn_cvt<<<8 * 256, 256, 0, stream>>>(m2_vg, m2_gg, m2g_bf, s2g, 256);
    cvt_w2_kernel<<<(512 * 1024) / 256, 256, 0, stream>>>(w2, w2m_bf);

    // ---- conv trunk ----
    conv_lds<<<768, 256, 0, stream>>>(feature, cw1, cb1, cbA, 448, 192, 8, 1);
    conv_lds<<<768, 256, 0, stream>>>(cbA, cw2, cb2, cbB, 256, 256, 8, 1);
    conv_lds<<<768, 256, 0, stream>>>(cbB, cw3, cb3, cbA, 384, 384, 8, 1);
    conv_lds<<<768, 256, 0, stream>>>(cbA, cw4, cb4, cbB, 256, 256, 8, 0);     // ->6x6
    conv_lds<<<128, 256, 0, stream>>>(cbB, cw5, cb5, featbuf, 768, 128, 6, 0); // ->4x4

    // ---- c1, Px/Py, Qx/Qy ----
    feat_c1_kernel<<<1024 / 4, 256, 0, stream>>>(featbuf, w1, b1, c1);
    pxy_kernel<<<(256 * 1024) / 256, 256, 0, stream>>>(sgrid, w1, c1, Px, Py);
    qxy_kernel<<<(256 * 512) / 256, 256, 0, stream>>>(sgrid, w2, Qx, Qy);

    // ---- fused per-position MLP: 2048 blocks x 32 rows, 2 blocks/CU ----
    size_t lds_bytes = (size_t)ROWS * RS * sizeof(unsigned short);   // 66048
    hipFuncSetAttribute(reinterpret_cast<const void*>(fused_mlp),
                        hipFuncAttributeMaxDynamicSharedMemorySize, (int)lds_bytes);
    fused_mlp<<<65536 / ROWS, 512, lds_bytes, stream>>>(
        Px, Py, Qx, Qy,
        m1f_bf, s1f, m1_bf, m1g_bf, s1g, m1_bg,
        w2m_bf, b2,
        m2f_bf, s2f, m2_bf, m2g_bf, s2g, m2_bg,
        w3, b3, out);
}

// Round 7
// 1609.033 us; speedup vs baseline: 2.0694x; 2.0694x over previous
//
#include <hip/hip_runtime.h>
#include <cmath>

#define LRELU(x) ((x) > 0.0f ? (x) : 0.01f * (x))

typedef __attribute__((ext_vector_type(8))) short short8;
typedef __attribute__((ext_vector_type(4))) float f32x4;
typedef __attribute__((ext_vector_type(2))) unsigned uint2v;

constexpr int RS = 1032;   // LDS master row stride (shorts); rows 8-short aligned

__device__ __forceinline__ unsigned short f2bf(float f) {
    unsigned u = __float_as_uint(f);
    unsigned r = (u + 0x7fff + ((u >> 16) & 1)) >> 16;   // RNE
    return (unsigned short)r;
}
__device__ __forceinline__ float bf2f(unsigned short h) {
    return __uint_as_float((unsigned)h << 16);
}
__device__ __forceinline__ unsigned pk2(unsigned short a, unsigned short b) {
    return (unsigned)a | ((unsigned)b << 16);
}

// ---------------------------------------------------------------------------
// sgrid[t][c] = sin(r_t * 2^((c/2)/2)), r_t=(t-128)*pi/256  (256 x 32)
// ---------------------------------------------------------------------------
__global__ void sgrid_kernel(float* __restrict__ sg) {
    int idx = blockIdx.x * blockDim.x + threadIdx.x;
    if (idx >= 256 * 32) return;
    int t = idx >> 5, c = idx & 31;
    double r = (double)(t - 128) * 3.14159265358979323846 / 256.0;
    double scale = exp2(0.5 * (double)(c >> 1));
    sg[idx] = (float)sin(r * scale);
}

// ---------------------------------------------------------------------------
// Grouped 3x3 conv + lrelu; weights staged coalesced into LDS.
// ---------------------------------------------------------------------------
__global__ __launch_bounds__(256) void conv_lds(
    const float* __restrict__ x, const float* __restrict__ w,
    const float* __restrict__ bias, float* __restrict__ y,
    int Cin_g, int Cout_g, int Hin, int pad) {
    __shared__ float wsh[6912];
    __shared__ float red[256];
    int oc = blockIdx.x;
    int Hout = pad ? Hin : Hin - 2;
    int t = threadIdx.x;
    int nw = Cin_g * 9;
    const float* wb = w + (size_t)oc * nw;
    for (int idx = t; idx < nw; idx += 256) wsh[idx] = wb[idx];
    __syncthreads();
    int p = t & 63, ch = t >> 6;
    int oy = p / Hout, ox = p % Hout;
    int g = oc / Cout_g;
    const float* xb = x + (size_t)g * Cin_g * Hin * Hin;
    bool valid = p < Hout * Hout;
    int S = (Cin_g + 3) >> 2;
    int ic0 = ch * S, ic1 = min(Cin_g, ic0 + S);
    float acc = 0.f;
    if (valid) {
        for (int ic = ic0; ic < ic1; ++ic) {
            const float* xc = xb + (size_t)ic * Hin * Hin;
            const float* wc = wsh + ic * 9;
            #pragma unroll
            for (int ky = 0; ky < 3; ++ky) {
                int iy = oy + ky - pad;
                if (iy < 0 || iy >= Hin) continue;
                #pragma unroll
                for (int kx = 0; kx < 3; ++kx) {
                    int ix = ox + kx - pad;
                    if (ix < 0 || ix >= Hin) continue;
                    acc = fmaf(xc[iy * Hin + ix], wc[ky * 3 + kx], acc);
                }
            }
        }
    }
    red[t] = acc;
    __syncthreads();
    if (t < 64 && valid) {
        float s = red[t] + red[t + 64] + red[t + 128] + red[t + 192] + bias[oc];
        y[(size_t)oc * Hout * Hout + p] = LRELU(s);
    }
}

// ---------------------------------------------------------------------------
// c1[o] = b1[o] + feat . w1[o][32:]
// ---------------------------------------------------------------------------
__global__ void feat_c1_kernel(const float* __restrict__ feat, const float* __restrict__ w1,
                               const float* __restrict__ b1, float* __restrict__ c1) {
    int o = (blockIdx.x * blockDim.x + threadIdx.x) >> 6;
    int lane = threadIdx.x & 63;
    if (o >= 1024) return;
    const float* wr = w1 + (size_t)o * 2080 + 32;
    float sum = 0.f;
    for (int k = lane; k < 2048; k += 64) sum += feat[k] * wr[k];
    #pragma unroll
    for (int off = 32; off; off >>= 1) sum += __shfl_xor(sum, off);
    if (lane == 0) c1[o] = sum + b1[o];
}

// ---------------------------------------------------------------------------
// wn_scale: s[r] = g[r]/||v[r,:]||  (block per row)
// ---------------------------------------------------------------------------
__global__ __launch_bounds__(256) void wn_scale(const float* __restrict__ v, const float* __restrict__ g,
                                                float* __restrict__ s, int K) {
    __shared__ float red[256];
    int r = blockIdx.x, t = threadIdx.x;
    const float* vr = v + (size_t)r * K;
    float sum = 0.f;
    for (int k = t; k < K; k += 256) { float x = vr[k]; sum = fmaf(x, x, sum); }
    red[t] = sum;
    __syncthreads();
    for (int o = 128; o; o >>= 1) {
        if (t < o) red[t] += red[t + o];
        __syncthreads();
    }
    if (t == 0) s[r] = g[r] / sqrtf(red[0]);
}

// ---------------------------------------------------------------------------
// repack: fp32 weights [T][N][ldk] -> bf16 MFMA fragment streams
// dst[((((t*W + w)*NT + nt)*KC + kc)*64 + l)*8 + e]
//   = f2bf(v[(t*N + w*NT*16 + nt*16 + (l&15))*ldk + koff + kc*32 + (l>>4)*8 + e])
// One wave load in the K-loop then reads 1 KB lane-contiguous.
// ---------------------------------------------------------------------------
__global__ void repack_kernel(const float* __restrict__ v, unsigned short* __restrict__ dst,
                              int T, int N, int K, int NT, int ldk, int koff) {
    int W = N / (NT * 16);
    int KC = K / 32;
    size_t total = (size_t)T * W * NT * KC * 64;
    size_t fi = (size_t)blockIdx.x * 256 + threadIdx.x;
    if (fi >= total) return;
    int l = fi & 63;
    size_t r = fi >> 6;
    int kc = r % KC; r /= KC;
    int nt = r % NT; r /= NT;
    int w  = r % W;  r /= W;
    int t  = (int)r;
    int n = w * NT * 16 + nt * 16 + (l & 15);
    int k = kc * 32 + (l >> 4) * 8;
    const float* src = v + ((size_t)t * N + n) * ldk + koff + k;
    unsigned short* d = dst + fi * 8;
    #pragma unroll
    for (int e = 0; e < 8; ++e) d[e] = f2bf(src[e]);
}

// ---------------------------------------------------------------------------
// Px/Py, Qx/Qy separable grid tables
// ---------------------------------------------------------------------------
__global__ void pxy_kernel(const float* __restrict__ sg, const float* __restrict__ w1,
                           const float* __restrict__ c1, float* __restrict__ Px,
                           float* __restrict__ Py) {
    int idx = blockIdx.x * 256 + threadIdx.x;  // 256*1024
    int t = idx >> 10, o = idx & 1023;
    const float* wr = w1 + (size_t)o * 2080;
    const float* sr = sg + t * 32;
    float px = 0.f, py = 0.f;
    #pragma unroll
    for (int k = 0; k < 16; ++k) {
        px = fmaf(sr[2 * k], wr[2 * k], px);
        py = fmaf(sr[2 * k + 1], wr[2 * k + 1], py);
    }
    Px[idx] = px + c1[o];
    Py[idx] = py;
}

__global__ void qxy_kernel(const float* __restrict__ sg, const float* __restrict__ w2,
                           float* __restrict__ Qx, float* __restrict__ Qy) {
    int idx = blockIdx.x * 256 + threadIdx.x;  // 256*512
    int t = idx >> 9, o = idx & 511;
    const float* wr = w2 + (size_t)o * 1056;
    const float* sr = sg + t * 32;
    float qx = 0.f, qy = 0.f;
    #pragma unroll
    for (int k = 0; k < 16; ++k) {
        qx = fmaf(sr[2 * k], wr[2 * k], qx);
        qy = fmaf(sr[2 * k + 1], wr[2 * k + 1], qy);
    }
    Qx[idx] = qx;
    Qy[idx] = qy;
}

// ---------------------------------------------------------------------------
// Fused MLP, 64-row blocks (1024 blocks -> minimum weight traffic).
// Swapped-operand MFMA: lane owns 4 consecutive cols at fixed row -> b64
// epilogue. Weights read from repacked fragment streams (coalesced 1KB/wave),
// depth-2 register prefetch. Master hi bf16 in LDS [64][RS]; stack-1 lo in
// VGPRs; stack-2 hi cols 0..511 / lo cols 512..1023.
// ---------------------------------------------------------------------------
__device__ __forceinline__ void step1(unsigned short* sm, int w, int l, int l15, int lq,
                                      int srcb, int dstb,
                                      const unsigned short* __restrict__ Bp,
                                      const float* __restrict__ sc,
                                      const float* __restrict__ bi,
                                      unsigned* lo_half) {
    f32x4 acc[4][4] = {};
    const unsigned short* wb = Bp + (size_t)w * (4 * 16 * 512) + (size_t)l * 8;
    const unsigned short* abase = sm + (size_t)l15 * RS + srcb + lq * 8;
    short8 b0[4], b1[4];
    #pragma unroll
    for (int nt = 0; nt < 4; ++nt) b0[nt] = *(const short8*)(wb + (size_t)(nt * 16 + 0) * 512);
    #pragma unroll
    for (int nt = 0; nt < 4; ++nt) b1[nt] = *(const short8*)(wb + (size_t)(nt * 16 + 1) * 512);
    #pragma unroll
    for (int kc = 0; kc < 16; ++kc) {
        short8 bn[4];
        if (kc < 14) {
            #pragma unroll
            for (int nt = 0; nt < 4; ++nt)
                bn[nt] = *(const short8*)(wb + (size_t)(nt * 16 + kc + 2) * 512);
        }
        short8 af[4];
        #pragma unroll
        for (int mt = 0; mt < 4; ++mt)
            af[mt] = *(const short8*)(abase + (size_t)(mt * 16) * RS + kc * 32);
        #pragma unroll
        for (int mt = 0; mt < 4; ++mt)
            #pragma unroll
            for (int nt = 0; nt < 4; ++nt)
                acc[mt][nt] = __builtin_amdgcn_mfma_f32_16x16x32_bf16(b0[nt], af[mt], acc[mt][nt], 0, 0, 0);
        #pragma unroll
        for (int nt = 0; nt < 4; ++nt) { b0[nt] = b1[nt]; b1[nt] = bn[nt]; }
    }
    #pragma unroll
    for (int nt = 0; nt < 4; ++nt) {
        int nb = w * 64 + nt * 16 + lq * 4;
        float4 s4 = *(const float4*)(sc + nb);
        float4 bb = *(const float4*)(bi + nb);
        #pragma unroll
        for (int mt = 0; mt < 4; ++mt) {
            int row = mt * 16 + l15;
            size_t hidx = (size_t)row * RS + dstb + nb;
            uint2v hold = *(uint2v*)(sm + hidx);
            unsigned* lp = lo_half + (mt * 4 + nt) * 2;
            float v0 = LRELU(acc[mt][nt][0] * s4.x + bb.x);
            float v1 = LRELU(acc[mt][nt][1] * s4.y + bb.y);
            float v2 = LRELU(acc[mt][nt][2] * s4.z + bb.z);
            float v3 = LRELU(acc[mt][nt][3] * s4.w + bb.w);
            v0 += bf2f((unsigned short)(hold[0] & 0xffffu)) + bf2f((unsigned short)(lp[0] & 0xffffu));
            v1 += bf2f((unsigned short)(hold[0] >> 16)) + bf2f((unsigned short)(lp[0] >> 16));
            v2 += bf2f((unsigned short)(hold[1] & 0xffffu)) + bf2f((unsigned short)(lp[1] & 0xffffu));
            v3 += bf2f((unsigned short)(hold[1] >> 16)) + bf2f((unsigned short)(lp[1] >> 16));
            unsigned short h0 = f2bf(v0), h1 = f2bf(v1), h2 = f2bf(v2), h3 = f2bf(v3);
            uint2v hnew; hnew[0] = pk2(h0, h1); hnew[1] = pk2(h2, h3);
            *(uint2v*)(sm + hidx) = hnew;
            lp[0] = pk2(f2bf(v0 - bf2f(h0)), f2bf(v1 - bf2f(h1)));
            lp[1] = pk2(f2bf(v2 - bf2f(h2)), f2bf(v3 - bf2f(h3)));
        }
    }
}

__device__ __forceinline__ void step2(unsigned short* sm, int w, int l, int l15, int lq,
                                      int srcb, int dstb,
                                      const unsigned short* __restrict__ Bp,
                                      const float* __restrict__ sc,
                                      const float* __restrict__ bi) {
    f32x4 acc[4][2] = {};
    const unsigned short* wb = Bp + (size_t)w * (2 * 8 * 512) + (size_t)l * 8;
    const unsigned short* abase = sm + (size_t)l15 * RS + srcb + lq * 8;
    short8 b0[2], b1[2];
    #pragma unroll
    for (int nt = 0; nt < 2; ++nt) b0[nt] = *(const short8*)(wb + (size_t)(nt * 8 + 0) * 512);
    #pragma unroll
    for (int nt = 0; nt < 2; ++nt) b1[nt] = *(const short8*)(wb + (size_t)(nt * 8 + 1) * 512);
    #pragma unroll
    for (int kc = 0; kc < 8; ++kc) {
        short8 bn[2];
        if (kc < 6) {
            #pragma unroll
            for (int nt = 0; nt < 2; ++nt)
                bn[nt] = *(const short8*)(wb + (size_t)(nt * 8 + kc + 2) * 512);
        }
        short8 af[4];
        #pragma unroll
        for (int mt = 0; mt < 4; ++mt)
            af[mt] = *(const short8*)(abase + (size_t)(mt * 16) * RS + kc * 32);
        #pragma unroll
        for (int mt = 0; mt < 4; ++mt)
            #pragma unroll
            for (int nt = 0; nt < 2; ++nt)
                acc[mt][nt] = __builtin_amdgcn_mfma_f32_16x16x32_bf16(b0[nt], af[mt], acc[mt][nt], 0, 0, 0);
        #pragma unroll
        for (int nt = 0; nt < 2; ++nt) { b0[nt] = b1[nt]; b1[nt] = bn[nt]; }
    }
    #pragma unroll
    for (int nt = 0; nt < 2; ++nt) {
        int nb = w * 32 + nt * 16 + lq * 4;
        float4 s4 = *(const float4*)(sc + nb);
        float4 bb = *(const float4*)(bi + nb);
        #pragma unroll
        for (int mt = 0; mt < 4; ++mt) {
            int row = mt * 16 + l15;
            size_t hidx = (size_t)row * RS + dstb + nb;
            uint2v hold = *(uint2v*)(sm + hidx);
            uint2v lold = *(uint2v*)(sm + hidx + 512);
            float v0 = LRELU(acc[mt][nt][0] * s4.x + bb.x);
            float v1 = LRELU(acc[mt][nt][1] * s4.y + bb.y);
            float v2 = LRELU(acc[mt][nt][2] * s4.z + bb.z);
            float v3 = LRELU(acc[mt][nt][3] * s4.w + bb.w);
            v0 += bf2f((unsigned short)(hold[0] & 0xffffu)) + bf2f((unsigned short)(lold[0] & 0xffffu));
            v1 += bf2f((unsigned short)(hold[0] >> 16)) + bf2f((unsigned short)(lold[0] >> 16));
            v2 += bf2f((unsigned short)(hold[1] & 0xffffu)) + bf2f((unsigned short)(lold[1] & 0xffffu));
            v3 += bf2f((unsigned short)(hold[1] >> 16)) + bf2f((unsigned short)(lold[1] >> 16));
            unsigned short h0 = f2bf(v0), h1 = f2bf(v1), h2 = f2bf(v2), h3 = f2bf(v3);
            uint2v hnew; hnew[0] = pk2(h0, h1); hnew[1] = pk2(h2, h3);
            uint2v lnew; lnew[0] = pk2(f2bf(v0 - bf2f(h0)), f2bf(v1 - bf2f(h1)));
            lnew[1] = pk2(f2bf(v2 - bf2f(h2)), f2bf(v3 - bf2f(h3)));
            *(uint2v*)(sm + hidx) = hnew;
            *(uint2v*)(sm + hidx + 512) = lnew;
        }
    }
}

__global__ __launch_bounds__(512, 2) void fused_mlp(
    const float* __restrict__ Px, const float* __restrict__ Py,
    const float* __restrict__ Qx, const float* __restrict__ Qy,
    const unsigned short* __restrict__ m1f, const float* __restrict__ s1f, const float* __restrict__ bf1,
    const unsigned short* __restrict__ m1g, const float* __restrict__ s1g, const float* __restrict__ bg1,
    const unsigned short* __restrict__ w2m, const float* __restrict__ b2,
    const unsigned short* __restrict__ m2f, const float* __restrict__ s2f, const float* __restrict__ bf2_,
    const unsigned short* __restrict__ m2g, const float* __restrict__ s2g, const float* __restrict__ bg2_,
    const float* __restrict__ w3, const float* __restrict__ b3,
    float* __restrict__ out) {
    extern __shared__ unsigned short sm[];     // [64][RS]
    int tid = threadIdx.x;
    int w = tid >> 6, l = tid & 63;
    int l15 = l & 15, lq = l >> 4;
    int n0 = blockIdx.x * 64;
    int i = n0 >> 8, jb = n0 & 255;

    unsigned lo_pk[64];   // stack-1 lo plane: [half(2)][mt(4)][nt(4)][pair(2)]

    // ---- P1: mid init; hi -> LDS (b64), lo -> VGPR ----
    #pragma unroll
    for (int h = 0; h < 2; ++h) {
        #pragma unroll
        for (int nt = 0; nt < 4; ++nt) {
            int nb = h * 512 + w * 64 + nt * 16 + lq * 4;
            float4 px4 = *(const float4*)(Px + (size_t)i * 1024 + nb);
            #pragma unroll
            for (int mt = 0; mt < 4; ++mt) {
                int row = mt * 16 + l15;
                float4 py4 = *(const float4*)(Py + (size_t)(jb + row) * 1024 + nb);
                float v0 = LRELU(px4.x + py4.x);
                float v1 = LRELU(px4.y + py4.y);
                float v2 = LRELU(px4.z + py4.z);
                float v3 = LRELU(px4.w + py4.w);
                unsigned short h0 = f2bf(v0), h1 = f2bf(v1), h2 = f2bf(v2), h3 = f2bf(v3);
                uint2v hv; hv[0] = pk2(h0, h1); hv[1] = pk2(h2, h3);
                *(uint2v*)(sm + (size_t)row * RS + nb) = hv;
                unsigned* lp = lo_pk + h * 32 + (mt * 4 + nt) * 2;
                lp[0] = pk2(f2bf(v0 - bf2f(h0)), f2bf(v1 - bf2f(h1)));
                lp[1] = pk2(f2bf(v2 - bf2f(h2)), f2bf(v3 - bf2f(h3)));
            }
        }
    }
    __syncthreads();

    // ---- P2: stack 1 ----
    for (int t = 0; t < 8; ++t) {
        step1(sm, w, l, l15, lq, 512, 0, m1f + (size_t)t * 512 * 512, s1f + t * 512, bf1 + t * 512, lo_pk);
        __syncthreads();
        step1(sm, w, l, l15, lq, 0, 512, m1g + (size_t)t * 512 * 512, s1g + t * 512, bg1 + t * 512, lo_pk + 32);
        __syncthreads();
    }

    // ---- P3: h2 = lrelu(Qx+Qy + mid @ w2m^T + b2); overwrite master ----
    {
        f32x4 acc[4][4] = {};
        const unsigned short* wb = w2m + (size_t)w * (4 * 32 * 512) + (size_t)l * 8;
        const unsigned short* abase = sm + (size_t)l15 * RS + lq * 8;
        short8 b0[4], b1[4];
        #pragma unroll
        for (int nt = 0; nt < 4; ++nt) b0[nt] = *(const short8*)(wb + (size_t)(nt * 32 + 0) * 512);
        #pragma unroll
        for (int nt = 0; nt < 4; ++nt) b1[nt] = *(const short8*)(wb + (size_t)(nt * 32 + 1) * 512);
        #pragma unroll
        for (int kc = 0; kc < 32; ++kc) {
            short8 bn[4];
            if (kc < 30) {
                #pragma unroll
                for (int nt = 0; nt < 4; ++nt)
                    bn[nt] = *(const short8*)(wb + (size_t)(nt * 32 + kc + 2) * 512);
            }
            short8 af[4];
            #pragma unroll
            for (int mt = 0; mt < 4; ++mt)
                af[mt] = *(const short8*)(abase + (size_t)(mt * 16) * RS + kc * 32);
            #pragma unroll
            for (int mt = 0; mt < 4; ++mt)
                #pragma unroll
                for (int nt = 0; nt < 4; ++nt)
                    acc[mt][nt] = __builtin_amdgcn_mfma_f32_16x16x32_bf16(b0[nt], af[mt], acc[mt][nt], 0, 0, 0);
            #pragma unroll
            for (int nt = 0; nt < 4; ++nt) { b0[nt] = b1[nt]; b1[nt] = bn[nt]; }
        }
        __syncthreads();   // all A reads of mid done before overwrite
        #pragma unroll
        for (int nt = 0; nt < 4; ++nt) {
            int nb = w * 64 + nt * 16 + lq * 4;      // 0..511
            float4 qx4 = *(const float4*)(Qx + (size_t)i * 512 + nb);
            float4 b24 = *(const float4*)(b2 + nb);
            #pragma unroll
            for (int mt = 0; mt < 4; ++mt) {
                int row = mt * 16 + l15;
                float4 qy4 = *(const float4*)(Qy + (size_t)(jb + row) * 512 + nb);
                float v0 = LRELU(acc[mt][nt][0] + qx4.x + qy4.x + b24.x);
                float v1 = LRELU(acc[mt][nt][1] + qx4.y + qy4.y + b24.y);
                float v2 = LRELU(acc[mt][nt][2] + qx4.z + qy4.z + b24.z);
                float v3 = LRELU(acc[mt][nt][3] + qx4.w + qy4.w + b24.w);
                unsigned short h0 = f2bf(v0), h1 = f2bf(v1), h2 = f2bf(v2), h3 = f2bf(v3);
                size_t hidx = (size_t)row * RS + nb;
                uint2v hv; hv[0] = pk2(h0, h1); hv[1] = pk2(h2, h3);
                uint2v lv; lv[0] = pk2(f2bf(v0 - bf2f(h0)), f2bf(v1 - bf2f(h1)));
                lv[1] = pk2(f2bf(v2 - bf2f(h2)), f2bf(v3 - bf2f(h3)));
                *(uint2v*)(sm + hidx) = hv;
                *(uint2v*)(sm + hidx + 512) = lv;
            }
        }
    }
    __syncthreads();

    // ---- P4: stack 2 ----
    for (int t = 0; t < 8; ++t) {
        step2(sm, w, l, l15, lq, 256, 0, m2f + (size_t)t * 256 * 256, s2f + t * 256, bf2_ + t * 256);
        __syncthreads();
        step2(sm, w, l, l15, lq, 0, 256, m2g + (size_t)t * 256 * 256, s2g + t * 256, bg2_ + t * 256);
        __syncthreads();
    }

    // ---- P5: rgb ----
    #pragma unroll
    for (int rr = 0; rr < 8; ++rr) {
        int row = w * 8 + rr;
        float s0 = 0.f, s1 = 0.f, s2 = 0.f;
        #pragma unroll
        for (int it = 0; it < 8; ++it) {
            int k = it * 64 + l;
            size_t hidx = (size_t)row * RS + k;
            float hv = bf2f(sm[hidx]) + bf2f(sm[hidx + 512]);
            s0 = fmaf(hv, w3[k], s0);
            s1 = fmaf(hv, w3[512 + k], s1);
            s2 = fmaf(hv, w3[1024 + k], s2);
        }
        #pragma unroll
        for (int off = 32; off; off >>= 1) {
            s0 += __shfl_xor(s0, off);
            s1 += __shfl_xor(s1, off);
            s2 += __shfl_xor(s2, off);
        }
        if (l == 0) {
            float v[3] = {s0 + b3[0], s1 + b3[1], s2 + b3[2]};
            #pragma unroll
            for (int c = 0; c < 3; ++c) {
                float sg = 1.0f / (1.0f + expf(-v[c]));
                out[(size_t)c * 65536 + n0 + row] = 1.1f * sg - 0.05f;
            }
        }
    }
}

extern "C" void kernel_launch(void* const* d_in, const int* in_sizes, int n_in,
                              void* d_out, int out_size, void* d_ws, size_t ws_size,
                              hipStream_t stream) {
    const float* feature = (const float*)d_in[0];
    const float* cw1 = (const float*)d_in[1];  const float* cb1 = (const float*)d_in[2];
    const float* cw2 = (const float*)d_in[3];  const float* cb2 = (const float*)d_in[4];
    const float* cw3 = (const float*)d_in[5];  const float* cb3 = (const float*)d_in[6];
    const float* cw4 = (const float*)d_in[7];  const float* cb4 = (const float*)d_in[8];
    const float* cw5 = (const float*)d_in[9];  const float* cb5 = (const float*)d_in[10];
    const float* w1  = (const float*)d_in[11]; const float* b1  = (const float*)d_in[12];
    const float* m1_vf = (const float*)d_in[13]; const float* m1_gf = (const float*)d_in[14];
    const float* m1_bf = (const float*)d_in[15];
    const float* m1_vg = (const float*)d_in[16]; const float* m1_gg = (const float*)d_in[17];
    const float* m1_bg = (const float*)d_in[18];
    const float* w2  = (const float*)d_in[19]; const float* b2  = (const float*)d_in[20];
    const float* m2_vf = (const float*)d_in[21]; const float* m2_gf = (const float*)d_in[22];
    const float* m2_bf = (const float*)d_in[23];
    const float* m2_vg = (const float*)d_in[24]; const float* m2_gg = (const float*)d_in[25];
    const float* m2_bg = (const float*)d_in[26];
    const float* w3  = (const float*)d_in[27]; const float* b3  = (const float*)d_in[28];
    float* out = (float*)d_out;

    float* ws = (float*)d_ws;
    size_t off = 0;
    float* sgrid   = ws + off; off += 256 * 32;
    float* cbA     = ws + off; off += 768 * 64;
    float* cbB     = ws + off; off += 768 * 64;
    float* featbuf = ws + off; off += 2048;
    float* c1      = ws + off; off += 1024;
    float* s1f     = ws + off; off += 8 * 512;
    float* s1g     = ws + off; off += 8 * 512;
    float* s2f     = ws + off; off += 8 * 256;
    float* s2g     = ws + off; off += 8 * 256;
    float* Px      = ws + off; off += 256 * 1024;
    float* Py      = ws + off; off += 256 * 1024;
    float* Qx      = ws + off; off += 256 * 512;
    float* Qy      = ws + off; off += 256 * 512;
    unsigned short* m1f_p = (unsigned short*)(ws + off); off += (size_t)8 * 512 * 512 / 2;
    unsigned short* m1g_p = (unsigned short*)(ws + off); off += (size_t)8 * 512 * 512 / 2;
    unsigned short* m2f_p = (unsigned short*)(ws + off); off += (size_t)8 * 256 * 256 / 2;
    unsigned short* m2g_p = (unsigned short*)(ws + off); off += (size_t)8 * 256 * 256 / 2;
    unsigned short* w2m_p = (unsigned short*)(ws + off); off += (size_t)512 * 1024 / 2;

    // ---- constants ----
    sgrid_kernel<<<32, 256, 0, stream>>>(sgrid);
    wn_scale<<<8 * 512, 256, 0, stream>>>(m1_vf, m1_gf, s1f, 512);
    wn_scale<<<8 * 512, 256, 0, stream>>>(m1_vg, m1_gg, s1g, 512);
    wn_scale<<<8 * 256, 256, 0, stream>>>(m2_vf, m2_gf, s2f, 256);
    wn_scale<<<8 * 256, 256, 0, stream>>>(m2_vg, m2_gg, s2g, 256);
    // fragment-stream repack (bf16)
    repack_kernel<<<1024, 256, 0, stream>>>(m1_vf, m1f_p, 8, 512, 512, 4, 512, 0);
    repack_kernel<<<1024, 256, 0, stream>>>(m1_vg, m1g_p, 8, 512, 512, 4, 512, 0);
    repack_kernel<<<256, 256, 0, stream>>>(m2_vf, m2f_p, 8, 256, 256, 2, 256, 0);
    repack_kernel<<<256, 256, 0, stream>>>(m2_vg, m2g_p, 8, 256, 256, 2, 256, 0);
    repack_kernel<<<256, 256, 0, stream>>>(w2, w2m_p, 1, 512, 1024, 4, 1056, 32);

    // ---- conv trunk ----
    conv_lds<<<768, 256, 0, stream>>>(feature, cw1, cb1, cbA, 448, 192, 8, 1);
    conv_lds<<<768, 256, 0, stream>>>(cbA, cw2, cb2, cbB, 256, 256, 8, 1);
    conv_lds<<<768, 256, 0, stream>>>(cbB, cw3, cb3, cbA, 384, 384, 8, 1);
    conv_lds<<<768, 256, 0, stream>>>(cbA, cw4, cb4, cbB, 256, 256, 8, 0);     // ->6x6
    conv_lds<<<128, 256, 0, stream>>>(cbB, cw5, cb5, featbuf, 768, 128, 6, 0); // ->4x4

    // ---- c1, Px/Py, Qx/Qy ----
    feat_c1_kernel<<<1024 / 4, 256, 0, stream>>>(featbuf, w1, b1, c1);
    pxy_kernel<<<(256 * 1024) / 256, 256, 0, stream>>>(sgrid, w1, c1, Px, Py);
    qxy_kernel<<<(256 * 512) / 256, 256, 0, stream>>>(sgrid, w2, Qx, Qy);

    // ---- fused per-position MLP: 1024 blocks x 64 rows ----
    size_t lds_bytes = (size_t)64 * RS * sizeof(unsigned short);   // 132096
    hipFuncSetAttribute(reinterpret_cast<const void*>(fused_mlp),
                        hipFuncAttributeMaxDynamicSharedMemorySize, (int)lds_bytes);
    fused_mlp<<<1024, 512, lds_bytes, stream>>>(
        Px, Py, Qx, Qy,
        m1f_p, s1f, m1_bf, m1g_p, s1g, m1_bg,
        w2m_p, b2,
        m2f_p, s2f, m2_bf, m2g_p, s2g, m2_bg,
        w3, b3, out);
}

// Round 8
// 1427.566 us; speedup vs baseline: 2.3324x; 1.1271x over previous
//
#include <hip/hip_runtime.h>
#include <cmath>

#define LRELU(x) fmaxf((x), 0.01f * (x))

typedef __attribute__((ext_vector_type(8))) short short8;
typedef __attribute__((ext_vector_type(4))) float f32x4;
typedef __attribute__((ext_vector_type(2))) unsigned uint2v;

constexpr int RS = 1032;   // LDS hi-plane row stride (shorts); RS/2=516 floats

__device__ __forceinline__ unsigned short f2bf(float f) {
    return __builtin_bit_cast(unsigned short, (__bf16)f);   // hw RNE cvt on gfx950
}
__device__ __forceinline__ float bf2f(unsigned short h) {
    return __uint_as_float((unsigned)h << 16);
}
__device__ __forceinline__ unsigned pk2(unsigned short a, unsigned short b) {
    return (unsigned)a | ((unsigned)b << 16);
}

// ---------------------------------------------------------------------------
// sgrid[t][c] = sin(r_t * 2^((c/2)/2))  (256 x 32, fp64 math)
// ---------------------------------------------------------------------------
__global__ void sgrid_kernel(float* __restrict__ sg) {
    int idx = blockIdx.x * blockDim.x + threadIdx.x;
    if (idx >= 256 * 32) return;
    int t = idx >> 5, c = idx & 31;
    double r = (double)(t - 128) * 3.14159265358979323846 / 256.0;
    double scale = exp2(0.5 * (double)(c >> 1));
    sg[idx] = (float)sin(r * scale);
}

// ---------------------------------------------------------------------------
// Conv: grid (oc, ic-chunk of 64), 256 thr = 64 px x 4 subs, LDS weights,
// LDS reduce, one atomicAdd per px per block.
// ---------------------------------------------------------------------------
__global__ __launch_bounds__(256) void conv_part(
    const float* __restrict__ x, const float* __restrict__ w,
    float* __restrict__ y, int Cin_g, int Cout_g, int Hin, int pad) {
    __shared__ float wsh[64 * 9];
    __shared__ float red[256];
    int oc = blockIdx.x, ch = blockIdx.y;
    int Hout = pad ? Hin : Hin - 2;
    int t = threadIdx.x;
    int ic0 = ch * 64;
    int nic = min(64, Cin_g - ic0);
    const float* wb = w + ((size_t)oc * Cin_g + ic0) * 9;
    for (int i = t; i < nic * 9; i += 256) wsh[i] = wb[i];
    __syncthreads();
    int p = t & 63, sub = t >> 6;
    int oy = p / Hout, ox = p % Hout;
    int g = oc / Cout_g;
    const float* xb = x + ((size_t)g * Cin_g + ic0) * Hin * Hin;
    bool valid = p < Hout * Hout;
    float acc = 0.f;
    if (valid) {
        for (int ic = sub; ic < nic; ic += 4) {
            const float* xc = xb + (size_t)ic * Hin * Hin;
            const float* wc = wsh + ic * 9;
            #pragma unroll
            for (int ky = 0; ky < 3; ++ky) {
                int iy = oy + ky - pad;
                if (iy < 0 || iy >= Hin) continue;
                #pragma unroll
                for (int kx = 0; kx < 3; ++kx) {
                    int ix = ox + kx - pad;
                    if (ix < 0 || ix >= Hin) continue;
                    acc = fmaf(xc[iy * Hin + ix], wc[ky * 3 + kx], acc);
                }
            }
        }
    }
    red[t] = acc;
    __syncthreads();
    if (t < 64 && valid)
        atomicAdd(&y[(size_t)oc * Hout * Hout + p],
                  red[t] + red[t + 64] + red[t + 128] + red[t + 192]);
}

__global__ void conv_finalize(float* __restrict__ y, const float* __restrict__ bias,
                              int HH, int n) {
    int i = blockIdx.x * 256 + threadIdx.x;
    if (i >= n) return;
    float v = y[i] + bias[i / HH];
    y[i] = LRELU(v);
}

// ---------------------------------------------------------------------------
// c1[o] = b1[o] + feat . w1[o][32:]
// ---------------------------------------------------------------------------
__global__ void feat_c1_kernel(const float* __restrict__ feat, const float* __restrict__ w1,
                               const float* __restrict__ b1, float* __restrict__ c1) {
    int o = (blockIdx.x * blockDim.x + threadIdx.x) >> 6;
    int lane = threadIdx.x & 63;
    if (o >= 1024) return;
    const float* wr = w1 + (size_t)o * 2080 + 32;
    float sum = 0.f;
    for (int k = lane; k < 2048; k += 64) sum += feat[k] * wr[k];
    #pragma unroll
    for (int off = 32; off; off >>= 1) sum += __shfl_xor(sum, off);
    if (lane == 0) c1[o] = sum + b1[o];
}

// ---------------------------------------------------------------------------
// wn_scale: s[r] = g[r]/||v[r,:]||
// ---------------------------------------------------------------------------
__global__ __launch_bounds__(256) void wn_scale(const float* __restrict__ v, const float* __restrict__ g,
                                                float* __restrict__ s, int K) {
    __shared__ float red[256];
    int r = blockIdx.x, t = threadIdx.x;
    const float* vr = v + (size_t)r * K;
    float sum = 0.f;
    for (int k = t; k < K; k += 256) { float x = vr[k]; sum = fmaf(x, x, sum); }
    red[t] = sum;
    __syncthreads();
    for (int o = 128; o; o >>= 1) {
        if (t < o) red[t] += red[t + o];
        __syncthreads();
    }
    if (t == 0) s[r] = g[r] / sqrtf(red[0]);
}

// ---------------------------------------------------------------------------
// repack: fp32 weights -> bf16 MFMA fragment streams (lane-contiguous 1KB/wave)
// ---------------------------------------------------------------------------
__global__ void repack_kernel(const float* __restrict__ v, unsigned short* __restrict__ dst,
                              int T, int N, int K, int NT, int ldk, int koff) {
    int W = N / (NT * 16);
    int KC = K / 32;
    size_t total = (size_t)T * W * NT * KC * 64;
    size_t fi = (size_t)blockIdx.x * 256 + threadIdx.x;
    if (fi >= total) return;
    int l = fi & 63;
    size_t r = fi >> 6;
    int kc = r % KC; r /= KC;
    int nt = r % NT; r /= NT;
    int w  = r % W;  r /= W;
    int t  = (int)r;
    int n = w * NT * 16 + nt * 16 + (l & 15);
    int k = kc * 32 + (l >> 4) * 8;
    const float* src = v + ((size_t)t * N + n) * ldk + koff + k;
    unsigned short* d = dst + fi * 8;
    #pragma unroll
    for (int e = 0; e < 8; ++e) d[e] = f2bf(src[e]);
}

// w2 repack with stack-2-aligned output-column ownership:
// col = (nt<2) ? w*32+nt*16+l15 : 256 + w*32 + (nt-2)*16 + l15
__global__ void repack_w2k(const float* __restrict__ w2, unsigned short* __restrict__ dst) {
    int fi = blockIdx.x * 256 + threadIdx.x;   // 8*4*32*64 = 65536
    if (fi >= 65536) return;
    int l = fi & 63;
    int r = fi >> 6;
    int kc = r & 31; r >>= 5;
    int nt = r & 3;  r >>= 2;
    int w = r;
    int l15 = l & 15;
    int col = (nt < 2) ? (w * 32 + nt * 16 + l15) : (256 + w * 32 + (nt - 2) * 16 + l15);
    int k = kc * 32 + (l >> 4) * 8;
    const float* src = w2 + (size_t)col * 1056 + 32 + k;
    unsigned short* d = dst + (size_t)fi * 8;
    #pragma unroll
    for (int e = 0; e < 8; ++e) d[e] = f2bf(src[e]);
}

// ---------------------------------------------------------------------------
// Px/Py, Qx/Qy separable grid tables
// ---------------------------------------------------------------------------
__global__ void pxy_kernel(const float* __restrict__ sg, const float* __restrict__ w1,
                           const float* __restrict__ c1, float* __restrict__ Px,
                           float* __restrict__ Py) {
    int idx = blockIdx.x * 256 + threadIdx.x;  // 256*1024
    int t = idx >> 10, o = idx & 1023;
    const float* wr = w1 + (size_t)o * 2080;
    const float* sr = sg + t * 32;
    float px = 0.f, py = 0.f;
    #pragma unroll
    for (int k = 0; k < 16; ++k) {
        px = fmaf(sr[2 * k], wr[2 * k], px);
        py = fmaf(sr[2 * k + 1], wr[2 * k + 1], py);
    }
    Px[idx] = px + c1[o];
    Py[idx] = py;
}

__global__ void qxy_kernel(const float* __restrict__ sg, const float* __restrict__ w2,
                           float* __restrict__ Qx, float* __restrict__ Qy) {
    int idx = blockIdx.x * 256 + threadIdx.x;  // 256*512
    int t = idx >> 9, o = idx & 511;
    const float* wr = w2 + (size_t)o * 1056;
    const float* sr = sg + t * 32;
    float qx = 0.f, qy = 0.f;
    #pragma unroll
    for (int k = 0; k < 16; ++k) {
        qx = fmaf(sr[2 * k], wr[2 * k], qx);
        qy = fmaf(sr[2 * k + 1], wr[2 * k + 1], qy);
    }
    Qx[idx] = qx;
    Qy[idx] = qy;
}

// ---------------------------------------------------------------------------
// Fused MLP. fp32 residual master lives in the OWNING WAVE'S VGPRs; LDS holds
// only the bf16 hi image (A-operand). Epilogue: v=lrelu(acc*s+b)+master;
// master=v; store hi. No lo plane, no hold read.
// ---------------------------------------------------------------------------
__device__ __forceinline__ void step1(unsigned short* sm, int w, int l, int l15, int lq,
                                      int srcb, int dstb,
                                      const unsigned short* __restrict__ Bp,
                                      const float* __restrict__ sc,
                                      const float* __restrict__ bi,
                                      f32x4* master) {
    f32x4 acc[4][4] = {};
    const unsigned short* wb = Bp + (size_t)w * (4 * 16 * 512) + (size_t)l * 8;
    const unsigned short* abase = sm + (size_t)l15 * RS + srcb + lq * 8;
    short8 b0[4], b1[4];
    #pragma unroll
    for (int nt = 0; nt < 4; ++nt) b0[nt] = *(const short8*)(wb + (size_t)(nt * 16 + 0) * 512);
    #pragma unroll
    for (int nt = 0; nt < 4; ++nt) b1[nt] = *(const short8*)(wb + (size_t)(nt * 16 + 1) * 512);
    #pragma unroll
    for (int kc = 0; kc < 16; ++kc) {
        short8 bn[4];
        if (kc < 14) {
            #pragma unroll
            for (int nt = 0; nt < 4; ++nt)
                bn[nt] = *(const short8*)(wb + (size_t)(nt * 16 + kc + 2) * 512);
        }
        short8 af[4];
        #pragma unroll
        for (int mt = 0; mt < 4; ++mt)
            af[mt] = *(const short8*)(abase + (size_t)(mt * 16) * RS + kc * 32);
        #pragma unroll
        for (int mt = 0; mt < 4; ++mt)
            #pragma unroll
            for (int nt = 0; nt < 4; ++nt)
                acc[mt][nt] = __builtin_amdgcn_mfma_f32_16x16x32_bf16(b0[nt], af[mt], acc[mt][nt], 0, 0, 0);
        #pragma unroll
        for (int nt = 0; nt < 4; ++nt) { b0[nt] = b1[nt]; b1[nt] = bn[nt]; }
    }
    #pragma unroll
    for (int nt = 0; nt < 4; ++nt) {
        int nb = w * 64 + nt * 16 + lq * 4;
        float4 s4 = *(const float4*)(sc + nb);
        float4 bb = *(const float4*)(bi + nb);
        #pragma unroll
        for (int mt = 0; mt < 4; ++mt) {
            int row = mt * 16 + l15;
            f32x4 m = master[mt * 4 + nt];
            float v0 = LRELU(acc[mt][nt][0] * s4.x + bb.x) + m[0];
            float v1 = LRELU(acc[mt][nt][1] * s4.y + bb.y) + m[1];
            float v2 = LRELU(acc[mt][nt][2] * s4.z + bb.z) + m[2];
            float v3 = LRELU(acc[mt][nt][3] * s4.w + bb.w) + m[3];
            m[0] = v0; m[1] = v1; m[2] = v2; m[3] = v3;
            master[mt * 4 + nt] = m;
            uint2v hv; hv[0] = pk2(f2bf(v0), f2bf(v1)); hv[1] = pk2(f2bf(v2), f2bf(v3));
            *(uint2v*)(sm + (size_t)row * RS + dstb + nb) = hv;
        }
    }
}

__device__ __forceinline__ void step2(unsigned short* sm, int w, int l, int l15, int lq,
                                      int srcb, int dstb,
                                      const unsigned short* __restrict__ Bp,
                                      const float* __restrict__ sc,
                                      const float* __restrict__ bi,
                                      f32x4* master) {
    f32x4 acc[4][2] = {};
    const unsigned short* wb = Bp + (size_t)w * (2 * 8 * 512) + (size_t)l * 8;
    const unsigned short* abase = sm + (size_t)l15 * RS + srcb + lq * 8;
    short8 b0[2], b1[2];
    #pragma unroll
    for (int nt = 0; nt < 2; ++nt) b0[nt] = *(const short8*)(wb + (size_t)(nt * 8 + 0) * 512);
    #pragma unroll
    for (int nt = 0; nt < 2; ++nt) b1[nt] = *(const short8*)(wb + (size_t)(nt * 8 + 1) * 512);
    #pragma unroll
    for (int kc = 0; kc < 8; ++kc) {
        short8 bn[2];
        if (kc < 6) {
            #pragma unroll
            for (int nt = 0; nt < 2; ++nt)
                bn[nt] = *(const short8*)(wb + (size_t)(nt * 8 + kc + 2) * 512);
        }
        short8 af[4];
        #pragma unroll
        for (int mt = 0; mt < 4; ++mt)
            af[mt] = *(const short8*)(abase + (size_t)(mt * 16) * RS + kc * 32);
        #pragma unroll
        for (int mt = 0; mt < 4; ++mt)
            #pragma unroll
            for (int nt = 0; nt < 2; ++nt)
                acc[mt][nt] = __builtin_amdgcn_mfma_f32_16x16x32_bf16(b0[nt], af[mt], acc[mt][nt], 0, 0, 0);
        #pragma unroll
        for (int nt = 0; nt < 2; ++nt) { b0[nt] = b1[nt]; b1[nt] = bn[nt]; }
    }
    #pragma unroll
    for (int nt = 0; nt < 2; ++nt) {
        int nb = w * 32 + nt * 16 + lq * 4;
        float4 s4 = *(const float4*)(sc + nb);
        float4 bb = *(const float4*)(bi + nb);
        #pragma unroll
        for (int mt = 0; mt < 4; ++mt) {
            int row = mt * 16 + l15;
            f32x4 m = master[mt * 2 + nt];
            float v0 = LRELU(acc[mt][nt][0] * s4.x + bb.x) + m[0];
            float v1 = LRELU(acc[mt][nt][1] * s4.y + bb.y) + m[1];
            float v2 = LRELU(acc[mt][nt][2] * s4.z + bb.z) + m[2];
            float v3 = LRELU(acc[mt][nt][3] * s4.w + bb.w) + m[3];
            m[0] = v0; m[1] = v1; m[2] = v2; m[3] = v3;
            master[mt * 2 + nt] = m;
            uint2v hv; hv[0] = pk2(f2bf(v0), f2bf(v1)); hv[1] = pk2(f2bf(v2), f2bf(v3));
            *(uint2v*)(sm + (size_t)row * RS + dstb + nb) = hv;
        }
    }
}

__global__ __launch_bounds__(512, 2) void fused_mlp(
    const float* __restrict__ Px, const float* __restrict__ Py,
    const float* __restrict__ Qx, const float* __restrict__ Qy,
    const unsigned short* __restrict__ m1f, const float* __restrict__ s1f, const float* __restrict__ bf1,
    const unsigned short* __restrict__ m1g, const float* __restrict__ s1g, const float* __restrict__ bg1,
    const unsigned short* __restrict__ w2m, const float* __restrict__ b2,
    const unsigned short* __restrict__ m2f, const float* __restrict__ s2f, const float* __restrict__ bf2_,
    const unsigned short* __restrict__ m2g, const float* __restrict__ s2g, const float* __restrict__ bg2_,
    const float* __restrict__ w3, const float* __restrict__ b3,
    float* __restrict__ out) {
    extern __shared__ unsigned short sm[];     // [64][RS] bf16 hi plane
    int tid = threadIdx.x;
    int w = tid >> 6, l = tid & 63;
    int l15 = l & 15, lq = l >> 4;
    int n0 = blockIdx.x * 64;
    int i = n0 >> 8, jb = n0 & 255;

    f32x4 mh[32];   // fp32 master: [half(2)][mt(4)][nt(4)]  (stack-2: [half][mt][nt2] in mh[0..7]/mh[16..23])

    // ---- P1: mid init; hi -> LDS, fp32 -> master regs ----
    #pragma unroll
    for (int h = 0; h < 2; ++h) {
        #pragma unroll
        for (int nt = 0; nt < 4; ++nt) {
            int nb = h * 512 + w * 64 + nt * 16 + lq * 4;
            float4 px4 = *(const float4*)(Px + (size_t)i * 1024 + nb);
            #pragma unroll
            for (int mt = 0; mt < 4; ++mt) {
                int row = mt * 16 + l15;
                float4 py4 = *(const float4*)(Py + (size_t)(jb + row) * 1024 + nb);
                f32x4 m;
                m[0] = LRELU(px4.x + py4.x);
                m[1] = LRELU(px4.y + py4.y);
                m[2] = LRELU(px4.z + py4.z);
                m[3] = LRELU(px4.w + py4.w);
                mh[h * 16 + mt * 4 + nt] = m;
                uint2v hv; hv[0] = pk2(f2bf(m[0]), f2bf(m[1])); hv[1] = pk2(f2bf(m[2]), f2bf(m[3]));
                *(uint2v*)(sm + (size_t)row * RS + nb) = hv;
            }
        }
    }
    __syncthreads();

    // ---- P2: stack 1 ----
    for (int t = 0; t < 8; ++t) {
        step1(sm, w, l, l15, lq, 512, 0, m1f + (size_t)t * 512 * 512, s1f + t * 512, bf1 + t * 512, mh);
        __syncthreads();
        step1(sm, w, l, l15, lq, 0, 512, m1g + (size_t)t * 512 * 512, s1g + t * 512, bg1 + t * 512, mh + 16);
        __syncthreads();
    }

    // ---- P3: h2 = lrelu(Qx+Qy + mid @ w2m^T + b2); re-init master ----
    {
        f32x4 acc[4][4] = {};
        const unsigned short* wb = w2m + (size_t)w * (4 * 32 * 512) + (size_t)l * 8;
        const unsigned short* abase = sm + (size_t)l15 * RS + lq * 8;
        short8 b0[4], b1[4];
        #pragma unroll
        for (int nt = 0; nt < 4; ++nt) b0[nt] = *(const short8*)(wb + (size_t)(nt * 32 + 0) * 512);
        #pragma unroll
        for (int nt = 0; nt < 4; ++nt) b1[nt] = *(const short8*)(wb + (size_t)(nt * 32 + 1) * 512);
        #pragma unroll
        for (int kc = 0; kc < 32; ++kc) {
            short8 bn[4];
            if (kc < 30) {
                #pragma unroll
                for (int nt = 0; nt < 4; ++nt)
                    bn[nt] = *(const short8*)(wb + (size_t)(nt * 32 + kc + 2) * 512);
            }
            short8 af[4];
            #pragma unroll
            for (int mt = 0; mt < 4; ++mt)
                af[mt] = *(const short8*)(abase + (size_t)(mt * 16) * RS + kc * 32);
            #pragma unroll
            for (int mt = 0; mt < 4; ++mt)
                #pragma unroll
                for (int nt = 0; nt < 4; ++nt)
                    acc[mt][nt] = __builtin_amdgcn_mfma_f32_16x16x32_bf16(b0[nt], af[mt], acc[mt][nt], 0, 0, 0);
            #pragma unroll
            for (int nt = 0; nt < 4; ++nt) { b0[nt] = b1[nt]; b1[nt] = bn[nt]; }
        }
        __syncthreads();   // all A reads of mid done before overwrite
        #pragma unroll
        for (int nt = 0; nt < 4; ++nt) {
            // stack-2-aligned ownership (matches repack_w2k)
            int colb = ((nt < 2) ? (w * 32 + nt * 16) : (256 + w * 32 + (nt - 2) * 16)) + lq * 4;
            float4 qx4 = *(const float4*)(Qx + (size_t)i * 512 + colb);
            float4 b24 = *(const float4*)(b2 + colb);
            #pragma unroll
            for (int mt = 0; mt < 4; ++mt) {
                int row = mt * 16 + l15;
                float4 qy4 = *(const float4*)(Qy + (size_t)(jb + row) * 512 + colb);
                f32x4 m;
                m[0] = LRELU(acc[mt][nt][0] + qx4.x + qy4.x + b24.x);
                m[1] = LRELU(acc[mt][nt][1] + qx4.y + qy4.y + b24.y);
                m[2] = LRELU(acc[mt][nt][2] + qx4.z + qy4.z + b24.z);
                m[3] = LRELU(acc[mt][nt][3] + qx4.w + qy4.w + b24.w);
                mh[(nt >> 1) * 16 + mt * 2 + (nt & 1)] = m;
                uint2v hv; hv[0] = pk2(f2bf(m[0]), f2bf(m[1])); hv[1] = pk2(f2bf(m[2]), f2bf(m[3]));
                *(uint2v*)(sm + (size_t)row * RS + colb) = hv;
            }
        }
    }
    __syncthreads();

    // ---- P4: stack 2 ----
    for (int t = 0; t < 8; ++t) {
        step2(sm, w, l, l15, lq, 256, 0, m2f + (size_t)t * 256 * 256, s2f + t * 256, bf2_ + t * 256, mh);
        __syncthreads();
        step2(sm, w, l, l15, lq, 0, 256, m2g + (size_t)t * 256 * 256, s2g + t * 256, bg2_ + t * 256, mh + 16);
        __syncthreads();
    }

    // ---- P5: dump fp32 master to LDS (float view, stride RS/2), then rgb ----
    __syncthreads();
    {
        float* smf = (float*)sm;
        #pragma unroll
        for (int hh = 0; hh < 2; ++hh)
            #pragma unroll
            for (int nt = 0; nt < 2; ++nt) {
                int colb = hh * 256 + w * 32 + nt * 16 + lq * 4;
                #pragma unroll
                for (int mt = 0; mt < 4; ++mt) {
                    int row = mt * 16 + l15;
                    f32x4 m = mh[hh * 16 + mt * 2 + nt];
                    *(f32x4*)(smf + (size_t)row * (RS / 2) + colb) = m;
                }
            }
    }
    __syncthreads();
    {
        const float* smf = (const float*)sm;
        #pragma unroll
        for (int rr = 0; rr < 8; ++rr) {
            int row = w * 8 + rr;
            float s0 = 0.f, s1 = 0.f, s2 = 0.f;
            #pragma unroll
            for (int it = 0; it < 8; ++it) {
                int k = it * 64 + l;
                float hv = smf[(size_t)row * (RS / 2) + k];
                s0 = fmaf(hv, w3[k], s0);
                s1 = fmaf(hv, w3[512 + k], s1);
                s2 = fmaf(hv, w3[1024 + k], s2);
            }
            #pragma unroll
            for (int off = 32; off; off >>= 1) {
                s0 += __shfl_xor(s0, off);
                s1 += __shfl_xor(s1, off);
                s2 += __shfl_xor(s2, off);
            }
            if (l == 0) {
                float v[3] = {s0 + b3[0], s1 + b3[1], s2 + b3[2]};
                #pragma unroll
                for (int c = 0; c < 3; ++c) {
                    float sg = 1.0f / (1.0f + expf(-v[c]));
                    out[(size_t)c * 65536 + n0 + row] = 1.1f * sg - 0.05f;
                }
            }
        }
    }
}

extern "C" void kernel_launch(void* const* d_in, const int* in_sizes, int n_in,
                              void* d_out, int out_size, void* d_ws, size_t ws_size,
                              hipStream_t stream) {
    const float* feature = (const float*)d_in[0];
    const float* cw1 = (const float*)d_in[1];  const float* cb1 = (const float*)d_in[2];
    const float* cw2 = (const float*)d_in[3];  const float* cb2 = (const float*)d_in[4];
    const float* cw3 = (const float*)d_in[5];  const float* cb3 = (const float*)d_in[6];
    const float* cw4 = (const float*)d_in[7];  const float* cb4 = (const float*)d_in[8];
    const float* cw5 = (const float*)d_in[9];  const float* cb5 = (const float*)d_in[10];
    const float* w1  = (const float*)d_in[11]; const float* b1  = (const float*)d_in[12];
    const float* m1_vf = (const float*)d_in[13]; const float* m1_gf = (const float*)d_in[14];
    const float* m1_bf = (const float*)d_in[15];
    const float* m1_vg = (const float*)d_in[16]; const float* m1_gg = (const float*)d_in[17];
    const float* m1_bg = (const float*)d_in[18];
    const float* w2  = (const float*)d_in[19]; const float* b2  = (const float*)d_in[20];
    const float* m2_vf = (const float*)d_in[21]; const float* m2_gf = (const float*)d_in[22];
    const float* m2_bf = (const float*)d_in[23];
    const float* m2_vg = (const float*)d_in[24]; const float* m2_gg = (const float*)d_in[25];
    const float* m2_bg = (const float*)d_in[26];
    const float* w3  = (const float*)d_in[27]; const float* b3  = (const float*)d_in[28];
    float* out = (float*)d_out;

    float* ws = (float*)d_ws;
    size_t off = 0;
    float* sgrid   = ws + off; off += 256 * 32;
    float* cbA     = ws + off; off += 768 * 64;
    float* cbB     = ws + off; off += 768 * 64;
    float* featbuf = ws + off; off += 2048;
    float* c1      = ws + off; off += 1024;
    float* s1f     = ws + off; off += 8 * 512;
    float* s1g     = ws + off; off += 8 * 512;
    float* s2f     = ws + off; off += 8 * 256;
    float* s2g     = ws + off; off += 8 * 256;
    float* Px      = ws + off; off += 256 * 1024;
    float* Py      = ws + off; off += 256 * 1024;
    float* Qx      = ws + off; off += 256 * 512;
    float* Qy      = ws + off; off += 256 * 512;
    unsigned short* m1f_p = (unsigned short*)(ws + off); off += (size_t)8 * 512 * 512 / 2;
    unsigned short* m1g_p = (unsigned short*)(ws + off); off += (size_t)8 * 512 * 512 / 2;
    unsigned short* m2f_p = (unsigned short*)(ws + off); off += (size_t)8 * 256 * 256 / 2;
    unsigned short* m2g_p = (unsigned short*)(ws + off); off += (size_t)8 * 256 * 256 / 2;
    unsigned short* w2m_p = (unsigned short*)(ws + off); off += (size_t)512 * 1024 / 2;

    // ---- constants ----
    sgrid_kernel<<<32, 256, 0, stream>>>(sgrid);
    wn_scale<<<8 * 512, 256, 0, stream>>>(m1_vf, m1_gf, s1f, 512);
    wn_scale<<<8 * 512, 256, 0, stream>>>(m1_vg, m1_gg, s1g, 512);
    wn_scale<<<8 * 256, 256, 0, stream>>>(m2_vf, m2_gf, s2f, 256);
    wn_scale<<<8 * 256, 256, 0, stream>>>(m2_vg, m2_gg, s2g, 256);
    repack_kernel<<<1024, 256, 0, stream>>>(m1_vf, m1f_p, 8, 512, 512, 4, 512, 0);
    repack_kernel<<<1024, 256, 0, stream>>>(m1_vg, m1g_p, 8, 512, 512, 4, 512, 0);
    repack_kernel<<<256, 256, 0, stream>>>(m2_vf, m2f_p, 8, 256, 256, 2, 256, 0);
    repack_kernel<<<256, 256, 0, stream>>>(m2_vg, m2g_p, 8, 256, 256, 2, 256, 0);
    repack_w2k<<<256, 256, 0, stream>>>(w2, w2m_p);

    // ---- conv trunk: zero -> partials (atomic) -> bias+lrelu ----
    hipMemsetAsync(cbA, 0, 768 * 64 * sizeof(float), stream);
    conv_part<<<dim3(768, 7), 256, 0, stream>>>(feature, cw1, cbA, 448, 192, 8, 1);
    conv_finalize<<<(768 * 64) / 256, 256, 0, stream>>>(cbA, cb1, 64, 768 * 64);
    hipMemsetAsync(cbB, 0, 768 * 64 * sizeof(float), stream);
    conv_part<<<dim3(768, 4), 256, 0, stream>>>(cbA, cw2, cbB, 256, 256, 8, 1);
    conv_finalize<<<(768 * 64) / 256, 256, 0, stream>>>(cbB, cb2, 64, 768 * 64);
    hipMemsetAsync(cbA, 0, 768 * 64 * sizeof(float), stream);
    conv_part<<<dim3(768, 6), 256, 0, stream>>>(cbB, cw3, cbA, 384, 384, 8, 1);
    conv_finalize<<<(768 * 64) / 256, 256, 0, stream>>>(cbA, cb3, 64, 768 * 64);
    hipMemsetAsync(cbB, 0, 768 * 36 * sizeof(float), stream);
    conv_part<<<dim3(768, 4), 256, 0, stream>>>(cbA, cw4, cbB, 256, 256, 8, 0);     // ->6x6
    conv_finalize<<<(768 * 36 + 255) / 256, 256, 0, stream>>>(cbB, cb4, 36, 768 * 36);
    hipMemsetAsync(featbuf, 0, 2048 * sizeof(float), stream);
    conv_part<<<dim3(128, 12), 256, 0, stream>>>(cbB, cw5, featbuf, 768, 128, 6, 0); // ->4x4
    conv_finalize<<<(2048 + 255) / 256, 256, 0, stream>>>(featbuf, cb5, 16, 2048);

    // ---- c1, Px/Py, Qx/Qy ----
    feat_c1_kernel<<<1024 / 4, 256, 0, stream>>>(featbuf, w1, b1, c1);
    pxy_kernel<<<(256 * 1024) / 256, 256, 0, stream>>>(sgrid, w1, c1, Px, Py);
    qxy_kernel<<<(256 * 512) / 256, 256, 0, stream>>>(sgrid, w2, Qx, Qy);

    // ---- fused per-position MLP: 1024 blocks x 64 rows ----
    size_t lds_bytes = (size_t)64 * RS * sizeof(unsigned short);   // 132096
    hipFuncSetAttribute(reinterpret_cast<const void*>(fused_mlp),
                        hipFuncAttributeMaxDynamicSharedMemorySize, (int)lds_bytes);
    fused_mlp<<<1024, 512, lds_bytes, stream>>>(
        Px, Py, Qx, Qy,
        m1f_p, s1f, m1_bf, m1g_p, s1g, m1_bg,
        w2m_p, b2,
        m2f_p, s2f, m2_bf, m2g_p, s2g, m2_bg,
        w3, b3, out);
}